// Round 1
// baseline (3636.348 us; speedup 1.0000x reference)
//
#include <hip/hip_runtime.h>

// LSTM decoder, MI355X. Persistent-kernel recurrence with device-scope flag
// barrier; W_hh/W_ih(action) slice resident in LDS as bf16 MFMA fragments.
// L=128, B=64, IN_F=ACT_F=512, H=1024.

#define LSTEPS 128
#define B 64
#define INF 512
#define ACTF 512
#define H 1024
#define KTOT 1536          // ACTF + H folded into the serial GEMM
#define NB 128             // persistent blocks (1 per CU max; 128 <= 256 CUs -> co-resident)
#define HC 8               // h-columns per block
#define LCOLS 32           // gate columns per block (4 gates x HC)
#define GSTR 33            // LDS gate tile leading-dim pad

typedef short s16x8 __attribute__((ext_vector_type(8)));   // 8 x bf16 (guide Sec.3)
typedef float f32x4 __attribute__((ext_vector_type(4)));
typedef unsigned short u16;

__device__ __forceinline__ u16 f2bf(float f) {
  return __builtin_bit_cast(u16, (__bf16)f);   // RNE
}
__device__ __forceinline__ float sigm(float x) { return 1.f / (1.f + __expf(-x)); }
__device__ __forceinline__ float tanh_fast(float x) { return 2.f / (1.f + __expf(-2.f * x)) - 1.f; }

// ---- setup: action_features fp32 -> bf16, natural [t*B+b][512] layout ----
__global__ void k_conv_act(const float* __restrict__ act, u16* __restrict__ actb) {
  int id = blockIdx.x * 256 + threadIdx.x;            // one 8-elem chunk per thread
  const float4* s = (const float4*)act + (size_t)id * 2;
  float4 a = s[0], b = s[1];
  s16x8 o;
  o[0] = (short)f2bf(a.x); o[1] = (short)f2bf(a.y); o[2] = (short)f2bf(a.z); o[3] = (short)f2bf(a.w);
  o[4] = (short)f2bf(b.x); o[5] = (short)f2bf(b.y); o[6] = (short)f2bf(b.z); o[7] = (short)f2bf(b.w);
  *((s16x8*)actb + id) = o;
}

// ---- setup: per-block W slice in MFMA B-fragment-contiguous order ----
// chunk index within block bk: ((kt*2 + T)*64 + lane); chunk holds
// W row local=T*16+(lane&15) (local=g*8+c -> j=g*1024+bk*8+c), k=kt*32+(lane>>4)*8 .. +7
// k<512 -> W_ih[j][512+k] (action part), else W_hh[j][k-512].
__global__ void k_build_wg(const float* __restrict__ Wih, const float* __restrict__ Whh,
                           u16* __restrict__ wg) {
  int bk = blockIdx.y;
  int lin = blockIdx.x * 256 + threadIdx.x;           // 0..6143
  int kt = lin >> 7, T = (lin >> 6) & 1, lane = lin & 63;
  int q = lane >> 4, r = lane & 15;
  int local = T * 16 + r;
  int j = (local >> 3) * 1024 + bk * 8 + (local & 7);
  int k = kt * 32 + q * 8;
  const float* src = (k < 512) ? (Wih + (size_t)j * 1024 + 512 + k)
                               : (Whh + (size_t)j * 1024 + (k - 512));
  s16x8 o;
#pragma unroll
  for (int e = 0; e < 8; ++e) o[e] = (short)f2bf(src[e]);
  ((s16x8*)wg)[(size_t)bk * 6144 + lin] = o;
}

// ---- setup: h0 -> bf16 ping buffer, zero barrier flags ----
__global__ void k_misc(const float* __restrict__ h0, u16* __restrict__ hbuf,
                       unsigned* __restrict__ flags) {
  int id = blockIdx.x * 256 + threadIdx.x;
  if (id < B * H) hbuf[id] = f2bf(h0[id]);
  if (id < NB) flags[id] = 0u;
}

// ---- setup: PRE0[bk][b][local] = IF@W_ih[:, :512]^T + b_ih + b_hh  (exact fp32) ----
__global__ void k_pre0(const float* __restrict__ inf, const float* __restrict__ Wih,
                       const float* __restrict__ bih, const float* __restrict__ bhh,
                       float* __restrict__ pre0) {
  int o = blockIdx.x * 256 + threadIdx.x;             // 0..262143
  int bk = o >> 11;
  int rr = o & 2047;
  int b = rr >> 5;
  int local = rr & 31;
  int j = (local >> 3) * 1024 + bk * 8 + (local & 7);
  const float4* xa = (const float4*)(inf + (size_t)b * INF);
  const float4* wa = (const float4*)(Wih + (size_t)j * 1024);
  float s = 0.f;
#pragma unroll 4
  for (int k = 0; k < 128; ++k) {
    float4 x = xa[k], w = wa[k];
    s += x.x * w.x + x.y * w.y + x.z * w.z + x.w * w.w;
  }
  pre0[o] = s + bih[j] + bhh[j];
}

// ---- persistent recurrent kernel ----
__global__ void __launch_bounds__(256, 1) k_rnn(
    const u16* __restrict__ actb, const u16* __restrict__ wg,
    const float* __restrict__ pre0, const float* __restrict__ cinit,
    u16* __restrict__ hbuf, unsigned* __restrict__ flags,
    float* __restrict__ out) {
  extern __shared__ char smem[];
  u16* wlds = (u16*)smem;                 // 98304 B: W fragments (persistent)
  float* gl = (float*)(smem + 98304);     // 64 x 33 fp32 gate tile (8448 B)

  const int tid = threadIdx.x;
  const int bk = blockIdx.x;
  const int w = tid >> 6;
  const int lane = tid & 63;
  const int q = lane >> 4, r = lane & 15;
  const int n0 = bk * HC;

  // stage W fragments once (coalesced 16B copies)
  {
    const s16x8* src = (const s16x8*)wg + (size_t)bk * 6144;
    s16x8* dst = (s16x8*)wlds;
    for (int i = tid; i < 6144; i += 256) dst[i] = src[i];
  }

  // cell state lives in registers across all 128 steps (2 elems/thread)
  const int p0 = tid, p1 = tid + 256;
  const int b0 = p0 >> 3, cc0 = p0 & 7;
  const int b1 = p1 >> 3, cc1 = p1 & 7;
  float cr0 = cinit[b0 * H + n0 + cc0];
  float cr1 = cinit[b1 * H + n0 + cc1];

  __syncthreads();

  const int kt0 = w * 12;                 // K split across 4 waves, no operand duplication
  for (int t = 0; t < LSTEPS; ++t) {
    const u16* hcur = hbuf + (t & 1) * (B * H);
    u16* hnxt = hbuf + ((t & 1) ^ 1) * (B * H);

    // init gate tile with PRE0
    for (int i = tid; i < B * LCOLS; i += 256)
      gl[(i >> 5) * GSTR + (i & 31)] = pre0[bk * (B * LCOLS) + i];
    __syncthreads();

    f32x4 acc[4][2];
#pragma unroll
    for (int mt = 0; mt < 4; ++mt) {
      f32x4 z = {0.f, 0.f, 0.f, 0.f};
      acc[mt][0] = z; acc[mt][1] = z;
    }

    const u16* atb = actb + (size_t)t * (B * ACTF);
#pragma unroll 4
    for (int kk = 0; kk < 12; ++kk) {
      const int kt = kt0 + kk;
      const int k = kt * 32 + q * 8;
      const s16x8* wb = (const s16x8*)wlds + kt * 128;
      s16x8 bf0 = wb[lane];               // conflict-free ds_read_b128
      s16x8 bf1 = wb[64 + lane];
#pragma unroll
      for (int mt = 0; mt < 4; ++mt) {
        const int m = mt * 16 + r;
        const u16* ap = (k < ACTF) ? (atb + m * ACTF + k)
                                   : (hcur + m * H + (k - ACTF));
        s16x8 af = *(const s16x8*)ap;
        acc[mt][0] = __builtin_amdgcn_mfma_f32_16x16x32_bf16(af, bf0, acc[mt][0], 0, 0, 0);
        acc[mt][1] = __builtin_amdgcn_mfma_f32_16x16x32_bf16(af, bf1, acc[mt][1], 0, 0, 0);
      }
    }

    // cross-wave K reduction into the gate tile
#pragma unroll
    for (int mt = 0; mt < 4; ++mt) {
      const int bb = mt * 16 + q * 4;
#pragma unroll
      for (int T = 0; T < 2; ++T) {
        const int lc = T * 16 + r;
#pragma unroll
        for (int e = 0; e < 4; ++e)
          atomicAdd(&gl[(bb + e) * GSTR + lc], acc[mt][T][e]);
      }
    }
    __syncthreads();

    // pointwise LSTM cell (2 (b, col) pairs per thread)
    float ig, fg, gg, og, hv0, hv1;
    ig = sigm(gl[b0 * GSTR + cc0]);
    fg = sigm(gl[b0 * GSTR + 8 + cc0]);
    gg = tanh_fast(gl[b0 * GSTR + 16 + cc0]);
    og = sigm(gl[b0 * GSTR + 24 + cc0]);
    cr0 = fg * cr0 + ig * gg;
    hv0 = og * tanh_fast(cr0);

    ig = sigm(gl[b1 * GSTR + cc1]);
    fg = sigm(gl[b1 * GSTR + 8 + cc1]);
    gg = tanh_fast(gl[b1 * GSTR + 16 + cc1]);
    og = sigm(gl[b1 * GSTR + 24 + cc1]);
    cr1 = fg * cr1 + ig * gg;
    hv1 = og * tanh_fast(cr1);

    // h1 -> next buffer: agent-scope write-through stores (visible at coherence
    // point once this wave's vmcnt drains; no reliance on L2 writeback)
    __hip_atomic_store(hnxt + b0 * H + n0 + cc0, f2bf(hv0), __ATOMIC_RELAXED, __HIP_MEMORY_SCOPE_AGENT);
    __hip_atomic_store(hnxt + b1 * H + n0 + cc1, f2bf(hv1), __ATOMIC_RELAXED, __HIP_MEMORY_SCOPE_AGENT);

    float* op = out + (size_t)t * (B * H);
    op[b0 * H + n0 + cc0] = hv0;
    op[b1 * H + n0 + cc1] = hv1;
    if (t == LSTEPS - 1) {
      float* hn = out + (size_t)LSTEPS * B * H;
      float* cn = hn + B * H;
      hn[b0 * H + n0 + cc0] = hv0; hn[b1 * H + n0 + cc1] = hv1;
      cn[b0 * H + n0 + cc0] = cr0; cn[b1 * H + n0 + cc1] = cr1;
    }

    if (t < LSTEPS - 1) {
      // drain this wave's h stores to the coherence point, then signal
      asm volatile("s_waitcnt vmcnt(0)" ::: "memory");
      __syncthreads();
      if (tid == 0)
        __hip_atomic_store(&flags[bk], (unsigned)(t + 1), __ATOMIC_RELAXED, __HIP_MEMORY_SCOPE_AGENT);
      if (tid < NB) {
        unsigned g = 0;
        while (__hip_atomic_load(&flags[tid], __ATOMIC_RELAXED, __HIP_MEMORY_SCOPE_AGENT) < (unsigned)(t + 1)) {
          __builtin_amdgcn_s_sleep(1);
          if (++g > (1u << 22)) break;   // bounded spin: wrong-answer beats hang
        }
      }
      __syncthreads();
      if (tid == 0) __threadfence();     // acquire side: invalidate stale L1/L2 h lines
      __syncthreads();
    }
  }
}

extern "C" void kernel_launch(void* const* d_in, const int* in_sizes, int n_in,
                              void* d_out, int out_size, void* d_ws, size_t ws_size,
                              hipStream_t stream) {
  const float* inf = (const float*)d_in[0];
  const float* act = (const float*)d_in[1];
  const float* h0  = (const float*)d_in[2];
  const float* cst = (const float*)d_in[3];
  const float* Wih = (const float*)d_in[4];
  const float* Whh = (const float*)d_in[5];
  const float* bih = (const float*)d_in[6];
  const float* bhh = (const float*)d_in[7];
  float* out = (float*)d_out;

  char* ws = (char*)d_ws;
  u16* actb      = (u16*)ws;                    //  8,388,608 B  act bf16
  u16* wg        = (u16*)(ws + 8388608);        // 12,582,912 B  W fragments bf16
  float* pre0    = (float*)(ws + 20971520);     //  1,048,576 B  PRE0 fp32
  u16* hbuf      = (u16*)(ws + 22020096);       //    262,144 B  h ping-pong bf16
  unsigned* flg  = (unsigned*)(ws + 22282240);  //        512 B  barrier flags

  hipLaunchKernelGGL(k_conv_act, dim3(2048), dim3(256), 0, stream, act, actb);
  hipLaunchKernelGGL(k_build_wg, dim3(24, 128), dim3(256), 0, stream, Wih, Whh, wg);
  hipLaunchKernelGGL(k_misc, dim3(256), dim3(256), 0, stream, h0, hbuf, flg);
  hipLaunchKernelGGL(k_pre0, dim3(1024), dim3(256), 0, stream, inf, Wih, bih, bhh, pre0);

  hipFuncSetAttribute((const void*)k_rnn, hipFuncAttributeMaxDynamicSharedMemorySize, 106752);
  hipLaunchKernelGGL(k_rnn, dim3(NB), dim3(256), 106752, stream,
                     actb, wg, pre0, cst, hbuf, flg, out);
}

// Round 2
// 2869.373 us; speedup vs baseline: 1.2673x; 1.2673x over previous
//
#include <hip/hip_runtime.h>

// LSTM decoder, MI355X. Persistent-kernel recurrence, fence-free:
// h travels producer->LLC->consumer via agent-scope write-through stores and
// agent-scope (cache-bypassing) atomic loads; flags likewise. No buffer_wbl2 /
// buffer_inv in the loop, so act/pre0/W stay cache-resident for all 128 steps.
// L=128, B=64, IN_F=ACT_F=512, H=1024.

#define LSTEPS 128
#define B 64
#define INF 512
#define ACTF 512
#define H 1024
#define NB 128             // persistent blocks, co-resident (128 <= 256 CUs)
#define HC 8               // h-columns per block
#define LCOLS 32           // gate columns per block (4 gates x HC)
#define GSTR 33            // LDS gate tile leading-dim pad

typedef short s16x8 __attribute__((ext_vector_type(8)));   // 8 x bf16
typedef float f32x4 __attribute__((ext_vector_type(4)));
typedef unsigned long u64x2 __attribute__((ext_vector_type(2)));
typedef unsigned short u16;

__device__ __forceinline__ u16 f2bf(float f) {
  return __builtin_bit_cast(u16, (__bf16)f);   // RNE
}
__device__ __forceinline__ float sigm(float x) { return 1.f / (1.f + __expf(-x)); }
__device__ __forceinline__ float tanh_fast(float x) { return 2.f / (1.f + __expf(-2.f * x)) - 1.f; }

// ---- setup: action_features fp32 -> bf16, natural [t*B+b][512] layout ----
__global__ void k_conv_act(const float* __restrict__ act, u16* __restrict__ actb) {
  int id = blockIdx.x * 256 + threadIdx.x;
  const float4* s = (const float4*)act + (size_t)id * 2;
  float4 a = s[0], b = s[1];
  s16x8 o;
  o[0] = (short)f2bf(a.x); o[1] = (short)f2bf(a.y); o[2] = (short)f2bf(a.z); o[3] = (short)f2bf(a.w);
  o[4] = (short)f2bf(b.x); o[5] = (short)f2bf(b.y); o[6] = (short)f2bf(b.z); o[7] = (short)f2bf(b.w);
  *((s16x8*)actb + id) = o;
}

// ---- setup: per-block W slice in MFMA B-fragment-contiguous order ----
__global__ void k_build_wg(const float* __restrict__ Wih, const float* __restrict__ Whh,
                           u16* __restrict__ wg) {
  int bk = blockIdx.y;
  int lin = blockIdx.x * 256 + threadIdx.x;           // 0..6143
  int kt = lin >> 7, T = (lin >> 6) & 1, lane = lin & 63;
  int q = lane >> 4, r = lane & 15;
  int local = T * 16 + r;
  int j = (local >> 3) * 1024 + bk * 8 + (local & 7);
  int k = kt * 32 + q * 8;
  const float* src = (k < 512) ? (Wih + (size_t)j * 1024 + 512 + k)
                               : (Whh + (size_t)j * 1024 + (k - 512));
  s16x8 o;
#pragma unroll
  for (int e = 0; e < 8; ++e) o[e] = (short)f2bf(src[e]);
  ((s16x8*)wg)[(size_t)bk * 6144 + lin] = o;
}

// ---- setup: h0 -> bf16 ping buffer, zero barrier flags ----
__global__ void k_misc(const float* __restrict__ h0, u16* __restrict__ hbuf,
                       unsigned* __restrict__ flags) {
  int id = blockIdx.x * 256 + threadIdx.x;
  if (id < B * H) hbuf[id] = f2bf(h0[id]);
  if (id < NB) flags[id] = 0u;
}

// ---- setup: PRE0 = IF@W_ih[:, :512]^T + b_ih + b_hh  (exact fp32) ----
__global__ void k_pre0(const float* __restrict__ inf, const float* __restrict__ Wih,
                       const float* __restrict__ bih, const float* __restrict__ bhh,
                       float* __restrict__ pre0) {
  int o = blockIdx.x * 256 + threadIdx.x;
  int bk = o >> 11;
  int rr = o & 2047;
  int b = rr >> 5;
  int local = rr & 31;
  int j = (local >> 3) * 1024 + bk * 8 + (local & 7);
  const float4* xa = (const float4*)(inf + (size_t)b * INF);
  const float4* wa = (const float4*)(Wih + (size_t)j * 1024);
  float s = 0.f;
#pragma unroll 4
  for (int k = 0; k < 128; ++k) {
    float4 x = xa[k], w = wa[k];
    s += x.x * w.x + x.y * w.y + x.z * w.z + x.w * w.w;
  }
  pre0[o] = s + bih[j] + bhh[j];
}

// ---- persistent recurrent kernel ----
__global__ void __launch_bounds__(256, 1) k_rnn(
    const u16* __restrict__ actb, const u16* __restrict__ wg,
    const float* __restrict__ pre0, const float* __restrict__ cinit,
    u16* __restrict__ hbuf, unsigned* __restrict__ flags,
    float* __restrict__ out) {
  extern __shared__ char smem[];
  u16* wlds = (u16*)smem;                 // 98304 B: W fragments (persistent)
  float* gl = (float*)(smem + 98304);     // 64 x 33 fp32 gate tile

  const int tid = threadIdx.x;
  const int bk = blockIdx.x;
  const int w = tid >> 6;
  const int lane = tid & 63;
  const int q = lane >> 4, r = lane & 15;
  const int n0 = bk * HC;

  {
    const s16x8* src = (const s16x8*)wg + (size_t)bk * 6144;
    s16x8* dst = (s16x8*)wlds;
    for (int i = tid; i < 6144; i += 256) dst[i] = src[i];
  }

  const int p0 = tid, p1 = tid + 256;
  const int b0 = p0 >> 3, cc0 = p0 & 7;
  const int b1 = p1 >> 3, cc1 = p1 & 7;
  float cr0 = cinit[b0 * H + n0 + cc0];
  float cr1 = cinit[b1 * H + n0 + cc1];

  __syncthreads();

  for (int t = 0; t < LSTEPS; ++t) {
    const u16* hcur = hbuf + (t & 1) * (B * H);
    u16* hnxt = hbuf + ((t & 1) ^ 1) * (B * H);

    // phase 1: init gate tile with PRE0 (reads stay L1/L2-warm: no inv anywhere)
    for (int i = tid; i < B * LCOLS; i += 256)
      gl[(i >> 5) * GSTR + (i & 31)] = pre0[bk * (B * LCOLS) + i];
    __syncthreads();

    f32x4 acc[4][2];
#pragma unroll
    for (int mt = 0; mt < 4; ++mt) {
      f32x4 z = {0.f, 0.f, 0.f, 0.f};
      acc[mt][0] = z; acc[mt][1] = z;
    }

    // phase 2: act-part MFMAs (no dependence on h(t-1)) — hidden under barrier
    const u16* atb = actb + (size_t)t * (B * ACTF);
#pragma unroll
    for (int kk = 0; kk < 4; ++kk) {
      const int kt = w * 4 + kk;                  // kt 0..15: pure action part
      const int k = kt * 32 + q * 8;
      const s16x8* wb = (const s16x8*)wlds + kt * 128;
      s16x8 bf0 = wb[lane];
      s16x8 bf1 = wb[64 + lane];
#pragma unroll
      for (int mt = 0; mt < 4; ++mt) {
        const int m = mt * 16 + r;
        s16x8 af = *(const s16x8*)(atb + m * ACTF + k);
        acc[mt][0] = __builtin_amdgcn_mfma_f32_16x16x32_bf16(af, bf0, acc[mt][0], 0, 0, 0);
        acc[mt][1] = __builtin_amdgcn_mfma_f32_16x16x32_bf16(af, bf1, acc[mt][1], 0, 0, 0);
      }
    }

    // phase 3: wait for h(t-1) to be published (t=0: h0 prestaged, no wait)
    if (t) {
      if (tid < NB) {
        unsigned g = 0;
        while (__hip_atomic_load(&flags[tid], __ATOMIC_RELAXED, __HIP_MEMORY_SCOPE_AGENT) < (unsigned)t) {
          __builtin_amdgcn_s_sleep(1);
          if (++g > (1u << 22)) break;   // bounded spin: wrong-answer beats hang
        }
      }
      __syncthreads();
      asm volatile("" ::: "memory");
    }

    // phase 4: h-part MFMAs — h read via agent-scope (LLC-direct) atomic loads
#pragma unroll
    for (int kk = 0; kk < 8; ++kk) {
      const int kt = 16 + w * 8 + kk;             // kt 16..47: h part
      const int k = kt * 32 + q * 8;
      const s16x8* wb = (const s16x8*)wlds + kt * 128;
      s16x8 bf0 = wb[lane];
      s16x8 bf1 = wb[64 + lane];
#pragma unroll
      for (int mt = 0; mt < 4; ++mt) {
        const int m = mt * 16 + r;
        const unsigned long* hp = (const unsigned long*)(hcur + m * H + (k - ACTF));
        unsigned long lo = __hip_atomic_load(hp, __ATOMIC_RELAXED, __HIP_MEMORY_SCOPE_AGENT);
        unsigned long hi = __hip_atomic_load(hp + 1, __ATOMIC_RELAXED, __HIP_MEMORY_SCOPE_AGENT);
        u64x2 v; v[0] = lo; v[1] = hi;
        s16x8 af = __builtin_bit_cast(s16x8, v);
        acc[mt][0] = __builtin_amdgcn_mfma_f32_16x16x32_bf16(af, bf0, acc[mt][0], 0, 0, 0);
        acc[mt][1] = __builtin_amdgcn_mfma_f32_16x16x32_bf16(af, bf1, acc[mt][1], 0, 0, 0);
      }
    }

    // phase 5: cross-wave K reduction into gate tile
#pragma unroll
    for (int mt = 0; mt < 4; ++mt) {
      const int bb = mt * 16 + q * 4;
#pragma unroll
      for (int T = 0; T < 2; ++T) {
        const int lc = T * 16 + r;
#pragma unroll
        for (int e = 0; e < 4; ++e)
          atomicAdd(&gl[(bb + e) * GSTR + lc], acc[mt][T][e]);
      }
    }
    __syncthreads();

    // phase 6: pointwise LSTM cell
    float ig, fg, gg, og, hv0, hv1;
    ig = sigm(gl[b0 * GSTR + cc0]);
    fg = sigm(gl[b0 * GSTR + 8 + cc0]);
    gg = tanh_fast(gl[b0 * GSTR + 16 + cc0]);
    og = sigm(gl[b0 * GSTR + 24 + cc0]);
    cr0 = fg * cr0 + ig * gg;
    hv0 = og * tanh_fast(cr0);

    ig = sigm(gl[b1 * GSTR + cc1]);
    fg = sigm(gl[b1 * GSTR + 8 + cc1]);
    gg = tanh_fast(gl[b1 * GSTR + 16 + cc1]);
    og = sigm(gl[b1 * GSTR + 24 + cc1]);
    cr1 = fg * cr1 + ig * gg;
    hv1 = og * tanh_fast(cr1);

    // h1: agent-scope write-through stores (reach LLC; vmcnt drain below orders
    // them before the flag store — manual release)
    __hip_atomic_store(hnxt + b0 * H + n0 + cc0, f2bf(hv0), __ATOMIC_RELAXED, __HIP_MEMORY_SCOPE_AGENT);
    __hip_atomic_store(hnxt + b1 * H + n0 + cc1, f2bf(hv1), __ATOMIC_RELAXED, __HIP_MEMORY_SCOPE_AGENT);

    float* op = out + (size_t)t * (B * H);
    op[b0 * H + n0 + cc0] = hv0;
    op[b1 * H + n0 + cc1] = hv1;
    if (t == LSTEPS - 1) {
      float* hn = out + (size_t)LSTEPS * B * H;
      float* cn = hn + B * H;
      hn[b0 * H + n0 + cc0] = hv0; hn[b1 * H + n0 + cc1] = hv1;
      cn[b0 * H + n0 + cc0] = cr0; cn[b1 * H + n0 + cc1] = cr1;
    }

    // phase 7: publish h(t): drain stores, block-join, signal. NO fence.
    if (t < LSTEPS - 1) {
      asm volatile("s_waitcnt vmcnt(0)" ::: "memory");
      __syncthreads();
      if (tid == 0)
        __hip_atomic_store(&flags[bk], (unsigned)(t + 1), __ATOMIC_RELAXED, __HIP_MEMORY_SCOPE_AGENT);
    }
  }
}

extern "C" void kernel_launch(void* const* d_in, const int* in_sizes, int n_in,
                              void* d_out, int out_size, void* d_ws, size_t ws_size,
                              hipStream_t stream) {
  const float* inf = (const float*)d_in[0];
  const float* act = (const float*)d_in[1];
  const float* h0  = (const float*)d_in[2];
  const float* cst = (const float*)d_in[3];
  const float* Wih = (const float*)d_in[4];
  const float* Whh = (const float*)d_in[5];
  const float* bih = (const float*)d_in[6];
  const float* bhh = (const float*)d_in[7];
  float* out = (float*)d_out;

  char* ws = (char*)d_ws;
  u16* actb      = (u16*)ws;                    //  8,388,608 B
  u16* wg        = (u16*)(ws + 8388608);        // 12,582,912 B
  float* pre0    = (float*)(ws + 20971520);     //  1,048,576 B
  u16* hbuf      = (u16*)(ws + 22020096);       //    262,144 B
  unsigned* flg  = (unsigned*)(ws + 22282240);  //        512 B

  hipLaunchKernelGGL(k_conv_act, dim3(2048), dim3(256), 0, stream, act, actb);
  hipLaunchKernelGGL(k_build_wg, dim3(24, 128), dim3(256), 0, stream, Wih, Whh, wg);
  hipLaunchKernelGGL(k_misc, dim3(256), dim3(256), 0, stream, h0, hbuf, flg);
  hipLaunchKernelGGL(k_pre0, dim3(1024), dim3(256), 0, stream, inf, Wih, bih, bhh, pre0);

  hipFuncSetAttribute((const void*)k_rnn, hipFuncAttributeMaxDynamicSharedMemorySize, 106752);
  hipLaunchKernelGGL(k_rnn, dim3(NB), dim3(256), 106752, stream,
                     actb, wg, pre0, cst, hbuf, flg, out);
}